// Round 11
// baseline (223.951 us; speedup 1.0000x reference)
//
#include <hip/hip_runtime.h>
#include <hip/hip_bf16.h>

#define D_MODEL 1024
#define NHEADS 16
#define HDIM 64
#define BATCH 8
#define SEQ 512
#define NROWS 4096          // BATCH*SEQ
#define SCALE 0.125f
#define LN_EPS 1e-5f

typedef __attribute__((ext_vector_type(8))) short bf16x8;      // 8 bf16 (4 VGPRs)
typedef __attribute__((ext_vector_type(4))) float f32x4;
typedef __attribute__((ext_vector_type(8))) unsigned short u16x8;

static __device__ __forceinline__ float bf2f(unsigned short u) {
    return __uint_as_float(((unsigned int)u) << 16);
}
static __device__ __forceinline__ unsigned short f2bf(float f) {
    unsigned int x = __float_as_uint(f);
    unsigned int r = (x + 0x7fffu + ((x >> 16) & 1u)) >> 16;   // RNE
    return (unsigned short)r;
}

// async 16B/lane global->LDS DMA; LDS dest = wave-uniform base + lane*16
#define GLOAD16(gp, lp)                                                        \
    __builtin_amdgcn_global_load_lds(                                          \
        (const __attribute__((address_space(1))) void*)(gp),                   \
        (__attribute__((address_space(3))) void*)(lp), 16, 0, 0)

// R20: counted-vmcnt pipeline primitives (kept for attn).
#define VMW(n) asm volatile("s_waitcnt vmcnt(" #n ")" ::: "memory")
#define RBAR() __builtin_amdgcn_s_barrier()

// ---------------------------------------------------------------------------
// Bias helper: jax.image.resize(bias128, (512,512), 'bilinear')
// ---------------------------------------------------------------------------
static __device__ __forceinline__ float bias128(int a, int b) {
    float d = fabsf((float)(a - b));
    return expf(-d * 0.1f) - d * 0.05f;
}

// ---------------------------------------------------------------------------
// prep_kernel (R24): LN wave-per-row (0..2047) + bias (2048..3071) +
// Wqkv convert (3072..6143) + Wout/Wgate convert (6144..8191, hoist/fused) +
// Wout TRANSPOSE -> WoutT_bf (8192..8447, fused) + bias2 matvec (8448..8451).
// bias2[n] = b_gate[n] + sum_k Wgate[n,k]*b_out[k]  (for og fusion, R24).
// ---------------------------------------------------------------------------
__global__ void prep_kernel(const float* __restrict__ dec, const float* __restrict__ enc,
                            const float* __restrict__ gamma, const float* __restrict__ beta,
                            const float* __restrict__ Wqkv,
                            const float* __restrict__ Wout, const float* __restrict__ Wgate,
                            const float* __restrict__ b_out, const float* __restrict__ b_gate,
                            unsigned short* __restrict__ q_ln, unsigned short* __restrict__ kv_ln,
                            float* __restrict__ bias, unsigned short* __restrict__ Wqkv_bf,
                            unsigned short* __restrict__ Wout_bf, unsigned short* __restrict__ Wgate_bf,
                            unsigned short* __restrict__ WoutT_bf, float* __restrict__ bias2) {
    int blk = blockIdx.x;
    int t = threadIdx.x;
    __shared__ unsigned short T[64 * 72];   // transpose bounce (9.2 KB)
    if (blk >= 8448) {          // bias2 matvec (4 blocks, fused only)
        int n = (blk - 8448) * 256 + t;
        float acc = 0.f;
        const float4* wg4 = (const float4*)(Wgate + (size_t)n * 1024);
        const float4* bo4 = (const float4*)b_out;
        for (int k = 0; k < 256; ++k) {
            float4 w = wg4[k]; float4 b = bo4[k];
            acc += w.x * b.x + w.y * b.y + w.z * b.z + w.w * b.w;
        }
        bias2[n] = acc + b_gate[n];
        return;
    }
    if (blk >= 8192) {          // Wout transpose -> WoutT_bf[j][k] = Wout[k][j]
        int tb = blk - 8192;
        int tr = tb >> 4, tc = tb & 15;     // tr: k-tile, tc: j-tile
        int r = t >> 2, q4 = (t & 3) * 16;
        const float* src = Wout + (size_t)(tr * 64 + r) * 1024 + tc * 64 + q4;
        #pragma unroll
        for (int p = 0; p < 4; ++p) {
            float4 v = ((const float4*)src)[p];
            T[(q4 + p * 4 + 0) * 72 + r] = f2bf(v.x);
            T[(q4 + p * 4 + 1) * 72 + r] = f2bf(v.y);
            T[(q4 + p * 4 + 2) * 72 + r] = f2bf(v.z);
            T[(q4 + p * 4 + 3) * 72 + r] = f2bf(v.w);
        }
        __syncthreads();
        unsigned short* dst = WoutT_bf + (size_t)(tc * 64 + r) * 1024 + tr * 64 + q4;
        *(u16x8*)(dst)     = *(const u16x8*)&T[r * 72 + q4];
        *(u16x8*)(dst + 8) = *(const u16x8*)&T[r * 72 + q4 + 8];
        return;
    }
    if (blk >= 6144) {          // hoisted Wout/Wgate convert
        int idx = (blk - 6144) * 256 + t;
        const float* src; unsigned short* dst; int off;
        if (idx < 262144) { src = Wout; dst = Wout_bf; off = idx; }
        else              { src = Wgate; dst = Wgate_bf; off = idx - 262144; }
        float4 v = ((const float4*)src)[off];
        ushort4 u;
        u.x = f2bf(v.x); u.y = f2bf(v.y); u.z = f2bf(v.z); u.w = f2bf(v.w);
        ((ushort4*)dst)[off] = u;
        return;
    }
    if (blk >= 3072) {          // Wqkv convert
        int idx = (blk - 3072) * 256 + t;
        float4 v = ((const float4*)Wqkv)[idx];
        ushort4 u;
        u.x = f2bf(v.x); u.y = f2bf(v.y); u.z = f2bf(v.z); u.w = f2bf(v.w);
        ((ushort4*)Wqkv_bf)[idx] = u;
        return;
    }
    if (blk >= 2048) {          // bias
        int idx = (blk - 2048) * 256 + t;
        int qi = idx >> 9, kj = idx & 511;
        float fq = (qi + 0.5f) * 0.25f - 0.5f;
        float fk = (kj + 0.5f) * 0.25f - 0.5f;
        int iq = (int)floorf(fq); float tq = fq - (float)iq;
        int ik = (int)floorf(fk); float tk = fk - (float)ik;
        int iq0 = min(max(iq, 0), 127), iq1 = min(max(iq + 1, 0), 127);
        int ik0 = min(max(ik, 0), 127), ik1 = min(max(ik + 1, 0), 127);
        float v = (1.f - tq) * ((1.f - tk) * bias128(iq0, ik0) + tk * bias128(iq0, ik1))
                +        tq  * ((1.f - tk) * bias128(iq1, ik0) + tk * bias128(iq1, ik1));
        bias[idx] = v;
        return;
    }
    // LN: wave-per-row, shuffle-only reduction (R22)
    int row = blk * 4 + (t >> 6);
    int lane = t & 63;
    const float* src = (row < NROWS) ? dec + (size_t)row * D_MODEL
                                     : enc + (size_t)(row - NROWS) * D_MODEL;
    unsigned short* dst = (row < NROWS) ? q_ln + (size_t)row * D_MODEL
                                        : kv_ln + (size_t)(row - NROWS) * D_MODEL;
    float4 x0 = ((const float4*)src)[lane];
    float4 x1 = ((const float4*)src)[lane + 64];
    float4 x2 = ((const float4*)src)[lane + 128];
    float4 x3 = ((const float4*)src)[lane + 192];
    float s  = x0.x + x0.y + x0.z + x0.w + x1.x + x1.y + x1.z + x1.w
             + x2.x + x2.y + x2.z + x2.w + x3.x + x3.y + x3.z + x3.w;
    float ss = x0.x * x0.x + x0.y * x0.y + x0.z * x0.z + x0.w * x0.w
             + x1.x * x1.x + x1.y * x1.y + x1.z * x1.z + x1.w * x1.w
             + x2.x * x2.x + x2.y * x2.y + x2.z * x2.z + x2.w * x2.w
             + x3.x * x3.x + x3.y * x3.y + x3.z * x3.z + x3.w * x3.w;
    #pragma unroll
    for (int off = 32; off > 0; off >>= 1) {
        s  += __shfl_down(s, off);
        ss += __shfl_down(ss, off);
    }
    s  = __shfl(s, 0);
    ss = __shfl(ss, 0);
    float mu  = s * (1.0f / 1024.0f);
    float var = ss * (1.0f / 1024.0f) - mu * mu;
    float rstd = rsqrtf(var + LN_EPS);
    #pragma unroll
    for (int j = 0; j < 4; ++j) {
        float4 xv = (j == 0) ? x0 : (j == 1) ? x1 : (j == 2) ? x2 : x3;
        float4 g  = ((const float4*)gamma)[lane + j * 64];
        float4 bb = ((const float4*)beta)[lane + j * 64];
        ushort4 u;
        u.x = f2bf((xv.x - mu) * rstd * g.x + bb.x);
        u.y = f2bf((xv.y - mu) * rstd * g.y + bb.y);
        u.z = f2bf((xv.z - mu) * rstd * g.z + bb.z);
        u.w = f2bf((xv.w - mu) * rstd * g.w + bb.w);
        ((ushort4*)dst)[lane + j * 64] = u;
    }
}

// ---------------------------------------------------------------------------
// Wout + Wgate fp32 -> bf16 (fallback path when ws too small to hoist)
// ---------------------------------------------------------------------------
__global__ void convert_og(const float* __restrict__ Wout, const float* __restrict__ Wgate,
                           unsigned short* __restrict__ Wout_bf, unsigned short* __restrict__ Wgate_bf) {
    int idx = blockIdx.x * 256 + threadIdx.x;
    const float* src; unsigned short* dst; int off;
    if (idx < 262144) { src = (const float*)Wout; dst = Wout_bf; off = idx; }
    else              { src = (const float*)Wgate; dst = Wgate_bf; off = idx - 262144; }
    float4 v = ((const float4*)src)[off];
    ushort4 u;
    u.x = f2bf(v.x); u.y = f2bf(v.y); u.z = f2bf(v.z); u.w = f2bf(v.w);
    ((ushort4*)dst)[off] = u;
}

// ===========================================================================
// MFMA GEMM cores (bf16). Permanent lessons:
// R7/R16: acc/frags NAMED scalars. R9: global_load_lds + XOR swizzle.
// R17: 128^2 tile latency-bound at K=1024. R18: attn KVBLK=128 regressed.
// R19: XCD ct-major swizzle FETCH 73->30MB. R20 NULL: counted-vmcnt on qkv.
// R21 WIN: qkv 24KB/6 blocks/CU 49.2->44.0. R22 WIN: og 4/CU + prep LN -4.7us.
// R23 NULL: attn XCD affinity + og BK=128 (kept, harmless).
// R24 (this round): og1+og2 FUSED via Wcomb = Wgate@Wout (algebraic identity
// gz = att@Wcomb^T + bias2). Wcomb GEMM rides in qkv's grid (128 lead blocks,
// same 64x128/BK=64 body, Wgate_bf x WoutT_bf). og2 + t_bf roundtrip gone.
// ===========================================================================
#define CSTR 136   // C-bounce row stride (multiple of 8 -> 16B-aligned rows)

#define MF(a, b, d) __builtin_amdgcn_mfma_f32_16x16x32_bf16((a), (b), (d), 0, 0, 0)

// ---------------------------------------------------------------------------
// QKV GEMM (R21/R24): 64x128 tile, BK=64 single-buffer (24 KB -> 6 blocks/CU),
// fused RoPE. Sections 0..2: q/k/v (grid tail, XCD swizzle). Section 3 (R24):
// first nwc blocks compute Wcomb[m][j] = sum_k Wgate[m,k]*Wout[k,j] with the
// identical GEMM body (A=Wgate_bf rows, B=WoutT_bf rows), direct bf16 store.
// ---------------------------------------------------------------------------
union alignas(16) SmemQS {
    struct { unsigned short A[64 * 64]; unsigned short B[128 * 64]; } ab;  // 24 KB
    unsigned short C[64 * CSTR];    // q/k bounce: 64 rows x 136 (17.4 KB)
    unsigned short Ct[128 * 72];    // v bounce (transposed): 128 d-rows x 72 (18.4 KB)
};

// one K-half (K=32) of a BK=64 step: 6 frag loads + 8 MFMA
#define QKH(pA, pB, kh)                                                        \
    {                                                                          \
        int pofs = (((kh) * 4 + quad) ^ x7) * 8;                               \
        const unsigned short* Ar_ = (pA) + (wr * 32 + c) * 64 + pofs;          \
        const unsigned short* Br_ = (pB) + (wc * 64 + c) * 64 + pofs;          \
        bf16x8 f0 = *(const bf16x8*)(Ar_);                                     \
        bf16x8 f1 = *(const bf16x8*)(Ar_ + 1024);                              \
        bf16x8 g0 = *(const bf16x8*)(Br_);                                     \
        bf16x8 g1 = *(const bf16x8*)(Br_ + 1024);                              \
        bf16x8 g2 = *(const bf16x8*)(Br_ + 2048);                              \
        bf16x8 g3 = *(const bf16x8*)(Br_ + 3072);                              \
        c00 = MF(f0, g0, c00); c01 = MF(f0, g1, c01); c02 = MF(f0, g2, c02); c03 = MF(f0, g3, c03); \
        c10 = MF(f1, g0, c10); c11 = MF(f1, g1, c11); c12 = MF(f1, g2, c12); c13 = MF(f1, g3, c13); \
    }

#define QROPE_REG(i, reg, A0, A1, A2, A3)                                      \
    {                                                                          \
        int mloc = wr * 32 + (i) * 16 + quad * 4 + (reg);                      \
        int crow = mloc * CSTR + wc * 64;                                      \
        float fl = (float)((rt * 64 + mloc) & 511);                            \
        float aa0 = fl * inv0, aa1 = fl * inv1;                                \
        float c0 = cosf(aa0), s0 = sinf(aa0);                                  \
        float c1 = cosf(aa1), s1 = sinf(aa1);                                  \
        float e0 = A0[(reg)], o0 = A2[(reg)];                                  \
        float e1 = A1[(reg)], o1 = A3[(reg)];                                  \
        smemq.C[crow + c]      = f2bf(e0 * c0 - o0 * s0);                      \
        smemq.C[crow + 32 + c] = f2bf(e0 * s0 + o0 * c0);                      \
        smemq.C[crow + 16 + c] = f2bf(e1 * c1 - o1 * s1);                      \
        smemq.C[crow + 48 + c] = f2bf(e1 * s1 + o1 * c1);                      \
    }
#define QROPE_ROW(i, A0, A1, A2, A3)                                           \
    QROPE_REG(i, 0, A0, A1, A2, A3) QROPE_REG(i, 1, A0, A1, A2, A3)            \
    QROPE_REG(i, 2, A0, A1, A2, A3) QROPE_REG(i, 3, A0, A1, A2, A3)

// V: bounce transposed — Ct[dcol][l_local], stride 72
#define QVSECT_REG(i, j, reg, Acc)                                             \
    smemq.Ct[(wc * 64 + (j) * 16 + c) * 72 + (wr * 32 + (i) * 16 + quad * 4 + (reg))] = f2bf(Acc[(reg)]);
#define QVSECT_TILE(i, j, Acc)                                                 \
    QVSECT_REG(i, j, 0, Acc) QVSECT_REG(i, j, 1, Acc)                          \
    QVSECT_REG(i, j, 2, Acc) QVSECT_REG(i, j, 3, Acc)

// R24: Wcomb direct store (section 3)
#define WC_TILE(i, j, Acc)                                                     \
    {                                                                          \
        int n_ = ct * 128 + wc * 64 + (j) * 16 + c;                            \
        int m_ = rt * 64 + wr * 32 + (i) * 16 + quad * 4;                      \
        Wcomb_bf[(size_t)(m_ + 0) * 1024 + n_] = f2bf(Acc[0]);                 \
        Wcomb_bf[(size_t)(m_ + 1) * 1024 + n_] = f2bf(Acc[1]);                 \
        Wcomb_bf[(size_t)(m_ + 2) * 1024 + n_] = f2bf(Acc[2]);                 \
        Wcomb_bf[(size_t)(m_ + 3) * 1024 + n_] = f2bf(Acc[3]);                 \
    }

__global__ __launch_bounds__(256, 6)
void qkv_gemm_mfma(const unsigned short* __restrict__ q_ln,
                   const unsigned short* __restrict__ kv_ln,
                   const unsigned short* __restrict__ Wb,
                   unsigned short* __restrict__ qo,
                   unsigned short* __restrict__ ko,
                   unsigned short* __restrict__ vo,
                   const unsigned short* __restrict__ Wgate_bf,
                   const unsigned short* __restrict__ WoutT_bf,
                   unsigned short* __restrict__ Wcomb_bf,
                   int nwc) {
    int bid = blockIdx.x;
    int section, ct, rt, n0;
    const unsigned short *A, *B;
    if (bid < nwc) {                          // R24 Wcomb blocks (lead, no tail)
        section = 3;
        rt = bid >> 3;                        // 0..15 (m-tiles of 64)
        ct = bid & 7;                         // 0..7  (j-tiles of 128)
        n0 = ct * 128;
        A = Wgate_bf; B = WoutT_bf;
    } else {
        int b2 = bid - nwc;                   // 0..1535
        int wg = (b2 & 7) * 192 + (b2 >> 3);  // XCD-contiguous (bijective)
        int st = wg >> 5, in = wg & 31;       // 48 super-tiles of 32 blocks
        int stc = st >> 4, str = st & 15;     // ct-major: stc = section
        ct = stc * 8 + (in & 7);              // 0..23
        rt = str * 4 + (in >> 3);             // 0..63
        n0 = ct * 128;
        section = stc;                        // 0=q 1=k 2=v
        A = (section == 0) ? q_ln : kv_ln;
        B = Wb;
    }

    __shared__ SmemQS smemq;
    unsigned short* As2 = smemq.ab.A;
    unsigned short* Bs2 = smemq.ab.B;
    int tid = threadIdx.x;
    int wave = tid >> 6, lane = tid & 63, quad = lane >> 4, c = lane & 15;
    int wr = wave >> 1, wc = wave & 1;
    int x7 = c & 7;

    // staging source: thread t covers row t>>3, slot t&7 holds chunk (t&7)^((t>>3)&7)
    int soff = (tid >> 3) * 1024 + (((tid & 7) ^ ((tid >> 3) & 7)) * 8);
    const unsigned short* Ab = A + (size_t)(rt * 64) * 1024 + soff;
    const unsigned short* Bb = B + (size_t)n0 * 1024 + soff;
    int stW = wave * 512;

    f32x4 c00 = (f32x4)0.f, c01 = (f32x4)0.f, c02 = (f32x4)0.f, c03 = (f32x4)0.f;
    f32x4 c10 = (f32x4)0.f, c11 = (f32x4)0.f, c12 = (f32x4)0.f, c13 = (f32x4)0.f;

    // Single-buffer BK=64 K-loop (16 steps); cross-block TLP hides stalls (R21).
    for (int kt = 0; kt < 16; ++kt) {
        int k0 = kt * 64;
        __syncthreads();
        GLOAD16(Ab + k0,          As2 + stW);
        GLOAD16(Ab + 32768 + k0,  As2 + stW + 2048);
        GLOAD16(Bb + k0,          Bs2 + stW);
        GLOAD16(Bb + 32768 + k0,  Bs2 + stW + 2048);
        GLOAD16(Bb + 65536 + k0,  Bs2 + stW + 4096);
        GLOAD16(Bb + 98304 + k0,  Bs2 + stW + 6144);
        __syncthreads();
        QKH(As2, Bs2, 0)
        QKH(As2, Bs2, 1)
    }

    __syncthreads();                    // all waves done reading As/Bs (union reuse)

    if (section == 3) {                 // Wcomb direct store
        WC_TILE(0, 0, c00) WC_TILE(0, 1, c01) WC_TILE(0, 2, c02) WC_TILE(0, 3, c03)
        WC_TILE(1, 0, c10) WC_TILE(1, 1, c11) WC_TILE(1, 2, c12) WC_TILE(1, 3, c13)
        return;
    }

    if (section == 2) {
        QVSECT_TILE(0, 0, c00) QVSECT_TILE(0, 1, c01) QVSECT_TILE(0, 2, c02) QVSECT_TILE(0, 3, c03)
        QVSECT_TILE(1, 0, c10) QVSECT_TILE(1, 1, c11) QVSECT_TILE(1, 2, c12) QVSECT_TILE(1, 3, c13)
        __syncthreads();
        // store: 128 d-rows x 64 contiguous l
        int dr = tid >> 1, hh = tid & 1;
        int h = ((n0 & 1023) >> 6) + (dr >> 6);
        int d = dr & 63;
        int mmb = rt * 64;
        int bb = mmb >> 9, ll0 = mmb & 511;
        unsigned short* orow = vo + (((size_t)bb * NHEADS + h) * HDIM + d) * SEQ + ll0 + hh * 32;
        const unsigned short* csrc = &smemq.Ct[dr * 72 + hh * 32];
        #pragma unroll
        for (int kc = 0; kc < 4; ++kc)
            *(u16x8*)(orow + kc * 8) = *(const u16x8*)(csrc + kc * 8);
        return;
    }

    float inv0 = expf(-0.2878231366f * (float)c);          // 10000^(-c/32)
    float inv1 = expf(-0.2878231366f * (float)(16 + c));
    QROPE_ROW(0, c00, c01, c02, c03)
    QROPE_ROW(1, c10, c11, c12, c13)
    __syncthreads();

    unsigned short* outp = (section == 0) ? qo : ko;
    int rr = tid >> 2;                  // row 0..63
    int ch = (tid >> 1) & 1;            // head-half 0/1
    int sub = tid & 1;                  // 32-short half within head
    int mm = rt * 64 + rr;
    int bb = mm >> 9, ll = mm & 511;
    int h = ((n0 & 1023) >> 6) + ch;
    unsigned short* orow = outp + (((size_t)bb * NHEADS + h) * SEQ + ll) * HDIM + sub * 32;
    const unsigned short* csrc = &smemq.C[rr * CSTR + ch * 64 + sub * 32];
    #pragma unroll
    for (int kc = 0; kc < 4; ++kc)
        *(u16x8*)(orow + kc * 8) = *(const u16x8*)(csrc + kc * 8);
}

// ---------------------------------------------------------------------------
// R24 FUSED output projection: one kernel computes t = att@Wout^T + b_out AND
// gz = att@Wcomb^T + bias2 (shared A-stage, dual B), then
// out = sigmoid(gz)*t + (1-sigmoid)*residual. 64x64 tile, BK=64, 24 KB LDS,
// grid 1024 (XCD swizzle), 4 blocks/CU. 8 named accumulators.
// ---------------------------------------------------------------------------
struct alignas(16) SmemF {
    unsigned short A[64 * 64];      // 8 KB
    unsigned short B1[64 * 64];     // 8 KB (Wout)
    unsigned short B2[64 * 64];     // 8 KB (Wcomb)
};

#define FUS_KH(kh)                                                             \
    {                                                                          \
        int pofs = (((kh) * 4 + quad) ^ x7) * 8;                               \
        const unsigned short* Ar_  = smf.A  + (wr * 32 + c) * 64 + pofs;       \
        const unsigned short* B1r_ = smf.B1 + (wc * 32 + c) * 64 + pofs;       \
        const unsigned short* B2r_ = smf.B2 + (wc * 32 + c) * 64 + pofs;       \
        bf16x8 f0 = *(const bf16x8*)(B1r_ - B1r_ + Ar_);                       \
        bf16x8 f1 = *(const bf16x8*)(Ar_ + 1024);                              \
        bf16x8 g0 = *(const bf16x8*)(B1r_);                                    \
        bf16x8 g1 = *(const bf16x8*)(B1r_ + 1024);                             \
        bf16x8 h0 = *(const bf16x8*)(B2r_);                                    \
        bf16x8 h1 = *(const bf16x8*)(B2r_ + 1024);                             \
        c00 = MF(f0, g0, c00); c01 = MF(f0, g1, c01);                          \
        c10 = MF(f1, g0, c10); c11 = MF(f1, g1, c11);                          \
        d00 = MF(f0, h0, d00); d01 = MF(f0, h1, d01);                          \
        d10 = MF(f1, h0, d10); d11 = MF(f1, h1, d11);                          \
    }

#define FO_TILE(i, j, CA, DA)                                                  \
    {                                                                          \
        int n = ct * 64 + wc * 32 + (j) * 16 + c;                              \
        float bo = b_out[n];                                                   \
        float b2v = bias2[n];                                                  \
        int mb = rt * 64 + wr * 32 + (i) * 16 + quad * 4;                      \
        _Pragma("unroll")                                                      \
        for (int r = 0; r < 4; ++r) {                                          \
            size_t idx = (size_t)(mb + r) * 1024 + n;                          \
            float tv = CA[r] + bo;                                             \
            float g = 1.0f / (1.0f + expf(-(DA[r] + b2v)));                    \
            out[idx] = g * tv + (1.0f - g) * residual[idx];                    \
        }                                                                      \
    }

__global__ __launch_bounds__(256, 4)
void out_fused_mfma(const unsigned short* __restrict__ att,
                    const unsigned short* __restrict__ Wob,
                    const unsigned short* __restrict__ Wcb,
                    const float* __restrict__ b_out,
                    const float* __restrict__ bias2,
                    const float* __restrict__ residual,
                    float* __restrict__ out) {
    int bid = blockIdx.x;                     // 0..1023
    int wg = (bid & 7) * 128 + (bid >> 3);    // XCD-contiguous, bijective
    int ct = wg & 15, rt = wg >> 4;
    __shared__ SmemF smf;
    int tid = threadIdx.x;
    int wave = tid >> 6, lane = tid & 63, quad = lane >> 4, c = lane & 15;
    int wr = wave >> 1, wc = wave & 1;
    int x7 = c & 7;
    int soff = (tid >> 3) * 1024 + (((tid & 7) ^ ((tid >> 3) & 7)) * 8);
    const unsigned short* Ab  = att + (size_t)(rt * 64) * 1024 + soff;
    const unsigned short* B1b = Wob + (size_t)(ct * 64) * 1024 + soff;
    const unsigned short* B2b = Wcb + (size_t)(ct * 64) * 1024 + soff;
    int stW = wave * 512;
    f32x4 c00 = (f32x4)0.f, c01 = (f32x4)0.f, c10 = (f32x4)0.f, c11 = (f32x4)0.f;
    f32x4 d00 = (f32x4)0.f, d01 = (f32x4)0.f, d10 = (f32x4)0.f, d11 = (f32x4)0.f;
    for (int kt = 0; kt < 16; ++kt) {
        int k0 = kt * 64;
        __syncthreads();
        GLOAD16(Ab + k0,           smf.A  + stW);
        GLOAD16(Ab + 32768 + k0,   smf.A  + stW + 2048);
        GLOAD16(B1b + k0,          smf.B1 + stW);
        GLOAD16(B1b + 32768 + k0,  smf.B1 + stW + 2048);
        GLOAD16(B2b + k0,          smf.B2 + stW);
        GLOAD16(B2b + 32768 + k0,  smf.B2 + stW + 2048);
        __syncthreads();
        FUS_KH(0)
        FUS_KH(1)
    }
    FO_TILE(0, 0, c00, d00) FO_TILE(0, 1, c01, d01)
    FO_TILE(1, 0, c10, d10) FO_TILE(1, 1, c11, d11)
}

// ---------------------------------------------------------------------------
// Out-projection GEMMs (R23, FALLBACK when ws too small for fusion):
// 64x64 tile, BK=128 single-buffer (32 KB LDS), grid 1024.
// ---------------------------------------------------------------------------
struct alignas(16) SmemOG {
    unsigned short A[64 * 128];     // 16 KB
    unsigned short B[64 * 128];     // 16 KB
};

#define OG_KH(kh)                                                              \
    {                                                                          \
        int pofs = (((kh) * 4 + quad) ^ c) * 8;                                \
        const unsigned short* Ar_ = smemog.A + (wr * 32 + c) * 128 + pofs;     \
        const unsigned short* Br_ = smemog.B + (wc * 32 + c) * 128 + pofs;     \
        bf16x8 f0 = *(const bf16x8*)(Ar_);                                     \
        bf16x8 f1 = *(const bf16x8*)(Ar_ + 2048);                              \
        bf16x8 g0 = *(const bf16x8*)(Br_);                                     \
        bf16x8 g1 = *(const bf16x8*)(Br_ + 2048);                              \
        c00 = MF(f0, g0, c00); c01 = MF(f0, g1, c01);                          \
        c10 = MF(f1, g0, c10); c11 = MF(f1, g1, c11);                          \
    }

#define OG_BODY(Aptr, Bptr)                                                    \
    int bid = blockIdx.x;                     /* 0..1023 */                    \
    int wg = (bid & 7) * 128 + (bid >> 3);    /* XCD-contiguous, bijective */  \
    int ct = wg & 15, rt = wg >> 4;                                            \
    int tid = threadIdx.x;                                                     \
    int wave = tid >> 6, lane = tid & 63, quad = lane >> 4, c = lane & 15;     \
    int wr = wave >> 1, wc = wave & 1;                                         \
    int soff = (tid >> 4) * 1024 + (((tid & 15) ^ ((tid >> 4) & 15)) * 8);     \
    const unsigned short* Ab = (Aptr) + (size_t)(rt * 64) * 1024 + soff;       \
    const unsigned short* Bb = (Bptr) + (size_t)(ct * 64) * 1024 + soff;       \
    int stW = wave * 512;                                                      \
    f32x4 c00 = (f32x4)0.f, c01 = (f32x4)0.f;                                  \
    f32x4 c10 = (f32x4)0.f, c11 = (f32x4)0.f;                                  \
    for (int kt = 0; kt < 8; ++kt) {                                           \
        int k0 = kt * 128;                                                     \
        __syncthreads();                                                       \
        GLOAD16(Ab + k0,          smemog.A + stW);                             \
        GLOAD16(Ab + 16384 + k0,  smemog.A + stW + 2048);                      \
        GLOAD16(Ab + 32768 + k0,  smemog.A + stW + 4096);                      \
        GLOAD16(Ab + 49152 + k0,  smemog.A + stW + 6144);                      \
        GLOAD16(Bb + k0,          smemog.B + stW);                             \
        GLOAD16(Bb + 16384 + k0,  smemog.B + stW + 2048);                      \
        GLOAD16(Bb + 32768 + k0,  smemog.B + stW + 4096);                      \
        GLOAD16(Bb + 49152 + k0,  smemog.B + stW + 6144);                      \
        __syncthreads();                                                       \
        OG_KH(0)                                                               \
        OG_KH(1)                                                               \
        OG_KH(2)                                                               \
        OG_KH(3)                                                               \
    }

#define O1_REG(mb, reg, n, Acc)                                                \
    t_bf[(size_t)((mb) + (reg)) * 1024 + (n)] = f2bf(Acc[(reg)] + bo);
#define O1_TILE(i, j, Acc)                                                     \
    {                                                                          \
        int n = ct * 64 + wc * 32 + (j) * 16 + c;                              \
        float bo = b_out[n];                                                   \
        int mb = rt * 64 + wr * 32 + (i) * 16 + quad * 4;                      \
        O1_REG(mb, 0, n, Acc) O1_REG(mb, 1, n, Acc)                            \
        O1_REG(mb, 2, n, Acc) O1_REG(mb, 3, n, Acc)                            \
    }

__global__ __launch_bounds__(256, 4)
void out_gemm1_mfma(const unsigned short* __restrict__ att,
                    const unsigned short* __restrict__ Wob,
                    const float* __restrict__ b_out,
                    unsigned short* __restrict__ t_bf) {
    __shared__ SmemOG smemog;
    OG_BODY(att, Wob)
    O1_TILE(0, 0, c00) O1_TILE(0, 1, c01)
    O1_TILE(1, 0, c10) O1_TILE(1, 1, c11)
}

#define O2_REG(mb, reg, n, Acc)                                                \
    {                                                                          \
        float gz = Acc[(reg)] + bg;                                            \
        float g = 1.0f / (1.0f + expf(-gz));                                   \
        size_t idx = (size_t)((mb) + (reg)) * 1024 + (n);                      \
        float tv = bf2f(t_bf[idx]);                                            \
        float rv = residual[idx];                                              \
        out[idx] = g * tv + (1.0f - g) * rv;                                   \
    }
#define O2_TILE(i, j, Acc)                                                     \
    {                                                                          \
        int n = ct * 64 + wc * 32 + (j) * 16 + c;                              \
        float bg = b_gate[n];                                                  \
        int mb = rt * 64 + wr * 32 + (i) * 16 + quad * 4;                      \
        O2_REG(mb, 0, n, Acc) O2_REG(mb, 1, n, Acc)                            \
        O2_REG(mb, 2, n, Acc) O2_REG(mb, 3, n, Acc)                            \
    }

__global__ __launch_bounds__(256, 4)
void out_gemm2_mfma(const unsigned short* __restrict__ t_bf,
                    const unsigned short* __restrict__ Wgb,
                    const float* __restrict__ b_gate,
                    const float* __restrict__ residual,
                    float* __restrict__ out) {
    __shared__ SmemOG smemog;
    OG_BODY(t_bf, Wgb)
    O2_TILE(0, 0, c00) O2_TILE(0, 1, c01)
    O2_TILE(1, 0, c10) O2_TILE(1, 1, c11)
}

// ---------------------------------------------------------------------------
// Flash attention (R23), bf16 MFMA (16x16x32). 128-row Q tile, 8 waves.
// R12 unnormalized streaming softmax; R15 K/Vt global_load_lds + XOR swizzle;
// R20 counted-vmcnt dbuf; R23 qt-major 1-D grid (head's K/V on one XCD).
// ---------------------------------------------------------------------------
#define KSTR 72   // Ps stride only

static __device__ __forceinline__ void attn_step(
    const unsigned short* __restrict__ KsB, const unsigned short* __restrict__ VsB,
    int kv0, const float* __restrict__ bias, unsigned short* __restrict__ Ps,
    int q0, int wb, int quad, int c, int p0, int p1,
    bf16x8 aq0, bf16x8 aq1, f32x4 (&oacc)[4], float (&lrow)[4])
{
    f32x4 sacc[4];
    #pragma unroll
    for (int nt = 0; nt < 4; ++nt) {
        const unsigned short* kbase = &KsB[(nt * 16 + c) * 64];
        bf16x8 b0 = *(const bf16x8*)(kbase + p0);
        bf16x8 b1 = *(const bf16x8*)(kbase + p1);
        f32x4 a = (f32x4)0.f;
        a = __builtin_amdgcn_mfma_f32_16x16x32_bf16(aq0, b0, a, 0, 0, 0);
        a = __builtin_amdgcn_mfma_f32_16x16x32_bf16(aq1, b1, a, 0, 0, 0);
        sacc[nt] = a;
    }
    const float* bbase = bias + (size_t)(q0 + wb + quad * 4) * 512 + kv0 + c;
    float tsum[4];
    #pragma unroll
    for (int r = 0; r < 4; ++r) tsum[r] = 0.f;
    #pragma unroll
    for (int nt = 0; nt < 4; ++nt)
        #pragma unroll
        for (int r = 0; r < 4; ++r) {
            float p = __expf(sacc[nt][r] * SCALE + bbase[(size_t)r * 512 + nt * 16]);
            tsum[r] += p;
            Ps[(wb + quad * 4 + r) * KSTR + nt * 16 + c] = f2bf(p);
        }
    #pragma unroll
    for (int r = 0; r < 4; ++r) {
        float t = tsum[r];
        t += __shfl_xor(t, 1);
        t += __shfl_xor(t, 2);
        t += __shfl_xor(t, 4);
        t += __shfl_xor(t, 8);
        lrow[r] += t;
    }
    bf16x8 pb0 = *(const bf16x8*)&Ps[(wb + c) * KSTR + quad * 8];
    bf16x8 pb1 = *(const bf16x8*)&Ps[(wb + c) * KSTR + 32 + quad * 8];
    #pragma unroll
    for (int t = 0; t < 4; ++t) {
        const unsigned short* vbase = &VsB[(t * 16 + c) * 64];
        bf16x8 a0 = *(const bf16x8*)(vbase + p0);
        bf16x8 a1 = *(const bf16x8*)(vbase + p1);
        oacc[t] = __builtin_amdgcn_mfma_f32_16x16x32_bf16(a0, pb0, oacc[t], 0, 0, 0);
        oacc[t] = __builtin_amdgcn_mfma_f32_16x16x32_bf16(a1, pb1, oacc[t], 0, 0, 0);
    }
}

// stage KV tile kvt into buffer BUF (2 loads/lane)
#define ASTAGE(BUF, kvt)                                                       \
    GLOAD16(kgb + (size_t)((kvt) * 64) * HDIM, Ks[BUF] + wave * 512);          \
    GLOAD16(vgb + (kvt) * 64, Vs[BUF] + wave * 512);

__global__ __launch_bounds__(512)
void attn_kernel(const unsigned short* __restrict__ q,
                 const unsigned short* __restrict__ k,
                 const unsigned short* __restrict__ vt,
                 const float* __restrict__ bias,
                 unsigned short* __restrict__ attended) {
    int bid = blockIdx.x;               // 0..511 (qt-major: bid%8 == hb%8)
    int qt = bid >> 7;                  // 0..3
    int hb = bid & 127;                 // 0..127
    int h = hb >> 3;                    // 0..15
    int b = hb & 7;                     // 0..7
    __shared__ unsigned short Ks[2][64 * 64];
    __shared__ unsigned short Vs[2][64 * 64];
    __shared__ unsigned short Ps[128 * KSTR];
    __shared__ float lf[128];

    int tid = threadIdx.x;
    int wave = tid >> 6, lane = tid & 63;   // wave 0..7
    int quad = lane >> 4, c = lane & 15;
    int wb = wave * 16;                     // wave's q-row base, 0..112
    size_t headbase = (((size_t)b * NHEADS + h) * SEQ) * HDIM;  // == (b*16+h)*32768
    int q0 = qt * 128;

    const unsigned short* qrow = q + headbase + (size_t)(q0 + wb + c) * HDIM;
    bf16x8 aq0 = *(const bf16x8*)(qrow + quad * 8);
    bf16x8 aq1 = *(const bf16x8*)(qrow + 32 + quad * 8);

    // staging: wave w covers rows w*8..w*8+7 (8 rows x 64 shorts = 1 GLOAD16/lane)
    int srow = wave * 8 + (lane >> 3);
    int schunk = (lane & 7) ^ (srow & 7);
    const unsigned short* kgb = k + headbase + (size_t)srow * HDIM + schunk * 8;
    const unsigned short* vgb = vt + headbase + (size_t)srow * SEQ + schunk * 8;
    int x7 = c & 7;
    int p0 = (quad ^ x7) * 8;
    int p1 = ((4 + quad) ^ x7) * 8;

    f32x4 oacc[4];
    #pragma unroll
    for (int t = 0; t < 4; ++t) oacc[t] = (f32x4)0.f;
    float lrow[4];
    #pragma unroll
    for (int r = 0; r < 4; ++r) lrow[r] = 0.f;

    // Counted-vmcnt dbuf pipeline: 8 KV tiles of 64, 2 loads/stage.
    ASTAGE(0, 0)
    ASTAGE(1, 1)
    VMW(2); RBAR();                               // tile0 ready (Q loads also drained)
    for (int kt2 = 0; kt2 < 4; ++kt2) {
        attn_step(Ks[0], Vs[0], (kt2 * 2) * 64, bias, Ps,
                  q0, wb, quad, c, p0, p1, aq0, aq1, oacc, lrow);
        RBAR();                                   // all waves done reading buf0
        if (kt2 < 3) { ASTAGE(0, kt2 * 2 + 2) VMW(2); }
        else         { VMW(0); }                  // tile7's loads must land
        RBAR();                                   // buf1 ready
        attn_step(Ks[1], Vs[1], (kt2 * 2 + 1) * 64, bias, Ps,
                  q0, wb, quad, c, p0, p1, aq0, aq1, oacc, lrow);
        RBAR();                                   // all waves done reading buf1
        if (kt2 < 3) { ASTAGE(1, kt2 * 2 + 3) VMW(2); }
        RBAR();                                   // buf0 ready (next iter)
    }

    if (c == 0) {
        f32x4 lv;
        lv[0] = lrow[0]; lv[1] = lrow[1]; lv[2] = lrow[2]; lv[3] = lrow[3];
        *(f32x4*)&lf[wb + quad * 4] = lv;
    }
    float invl = 1.0f / lf[wb + c];
    unsigned short* drow = attended + ((size_t)b * SEQ + (q0 + wb + c)) * D_MODEL + h * HDIM;
    #pragma unroll
    for (int t = 0; t < 4; ++t) {
        ushort4 o;
        o.x = f2bf(oacc[t][0] * invl);
        o.y = f2bf(oacc[t][1] * invl);
        o.z = f2bf(oacc[t][2] * invl);
        o.w = f2bf(oacc[t][3] * invl);
        *(ushort4*)(drow + t * 16 + quad * 4) = o;
    }
}

extern "C" void kernel_launch(void* const* d_in, const int* in_sizes, int n_in,
                              void* d_out, int out_size, void* d_ws, size_t ws_size,
                              hipStream_t stream) {
    const float* dec    = (const float*)d_in[0];
    const float* enc    = (const float*)d_in[1];
    const float* Wqkv   = (const float*)d_in[2];
    const float* Wout   = (const float*)d_in[3];
    const float* b_out  = (const float*)d_in[4];
    const float* Wgate  = (const float*)d_in[5];
    const float* b_gate = (const float*)d_in[6];
    const float* gamma  = (const float*)d_in[7];
    const float* beta   = (const float*)d_in[8];
    float* out = (float*)d_out;

    char* ws = (char*)d_ws;
    const size_t MB = 1024 * 1024;
    unsigned short* q_ln    = (unsigned short*)(ws + 0 * MB);
    unsigned short* kv_ln   = (unsigned short*)(ws + 8 * MB);
    unsigned short* qb      = (unsigned short*)(ws + 16 * MB);
    unsigned short* kb      = (unsigned short*)(ws + 24 * MB);
    unsigned short* vb      = (unsigned short*)(ws + 32 * MB);   // V^T (B,H,64,L)
    unsigned short* Wqkv_bf = (unsigned short*)(ws + 40 * MB);
    float*          bias    = (float*)(ws + 46 * MB);
    unsigned short* att     = (unsigned short*)(ws + 0 * MB);    // q_ln dead after qkv
    unsigned short* t_bf    = (unsigned short*)(ws + 24 * MB);   // kb dead after attn (fallback)

    bool hoist = (ws_size >= 51 * MB);
    bool fused = (ws_size >= 56 * MB);   // R24 og-fusion path
    unsigned short* Wout_bf  = (unsigned short*)(ws + (hoist ? 47 * MB : 32 * MB));
    unsigned short* Wgate_bf = (unsigned short*)(ws + (hoist ? 49 * MB : 34 * MB));
    unsigned short* WoutT_bf = (unsigned short*)(ws + 51 * MB);  // fused only
    unsigned short* Wcomb_bf = (unsigned short*)(ws + 53 * MB);  // fused only
    float*          bias2    = (float*)(ws + 55 * MB);           // fused only (4 KB)

    prep_kernel<<<fused ? 8452 : (hoist ? 8192 : 6144), 256, 0, stream>>>(
        dec, enc, gamma, beta, Wqkv, Wout, Wgate, b_out, b_gate,
        q_ln, kv_ln, bias, Wqkv_bf, Wout_bf, Wgate_bf, WoutT_bf, bias2);
    qkv_gemm_mfma<<<fused ? 1664 : 1536, 256, 0, stream>>>(
        q_ln, kv_ln, Wqkv_bf, qb, kb, vb,
        Wgate_bf, WoutT_bf, Wcomb_bf, fused ? 128 : 0);
    attn_kernel<<<512, 512, 0, stream>>>(qb, kb, vb, bias, att);
    if (!hoist)
        convert_og<<<2048, 256, 0, stream>>>(Wout, Wgate, Wout_bf, Wgate_bf);
    if (fused) {
        out_fused_mfma<<<1024, 256, 0, stream>>>(att, Wout_bf, Wcomb_bf, b_out, bias2, dec, out);
    } else {
        out_gemm1_mfma<<<1024, 256, 0, stream>>>(att, Wout_bf, b_out, t_bf);
        out_gemm2_mfma<<<1024, 256, 0, stream>>>(t_bf, Wgate_bf, b_gate, dec, out);
    }
}

// Round 12
// 199.140 us; speedup vs baseline: 1.1246x; 1.1246x over previous
//
#include <hip/hip_runtime.h>
#include <hip/hip_bf16.h>

#define D_MODEL 1024
#define NHEADS 16
#define HDIM 64
#define BATCH 8
#define SEQ 512
#define NROWS 4096          // BATCH*SEQ
#define SCALE 0.125f
#define LN_EPS 1e-5f

typedef __attribute__((ext_vector_type(8))) short bf16x8;      // 8 bf16 (4 VGPRs)
typedef __attribute__((ext_vector_type(4))) float f32x4;
typedef __attribute__((ext_vector_type(8))) unsigned short u16x8;

static __device__ __forceinline__ float bf2f(unsigned short u) {
    return __uint_as_float(((unsigned int)u) << 16);
}
static __device__ __forceinline__ unsigned short f2bf(float f) {
    unsigned int x = __float_as_uint(f);
    unsigned int r = (x + 0x7fffu + ((x >> 16) & 1u)) >> 16;   // RNE
    return (unsigned short)r;
}

// async 16B/lane global->LDS DMA; LDS dest = wave-uniform base + lane*16
#define GLOAD16(gp, lp)                                                        \
    __builtin_amdgcn_global_load_lds(                                          \
        (const __attribute__((address_space(1))) void*)(gp),                   \
        (__attribute__((address_space(3))) void*)(lp), 16, 0, 0)

// R20: counted-vmcnt pipeline primitives (kept for attn).
#define VMW(n) asm volatile("s_waitcnt vmcnt(" #n ")" ::: "memory")
#define RBAR() __builtin_amdgcn_s_barrier()

// ---------------------------------------------------------------------------
// Bias helper: jax.image.resize(bias128, (512,512), 'bilinear')
// ---------------------------------------------------------------------------
static __device__ __forceinline__ float bias128(int a, int b) {
    float d = fabsf((float)(a - b));
    return expf(-d * 0.1f) - d * 0.05f;
}

// ---------------------------------------------------------------------------
// prep_kernel (R22): LN wave-per-row (blocks 0..2047, 4 rows/block, NO
// barriers/LDS) + bias (2048..3071) + Wqkv convert (3072..6143) +
// [hoisted Wout/Wgate convert (6144..8191)]
// ---------------------------------------------------------------------------
__global__ void prep_kernel(const float* __restrict__ dec, const float* __restrict__ enc,
                            const float* __restrict__ gamma, const float* __restrict__ beta,
                            const float* __restrict__ Wqkv,
                            const float* __restrict__ Wout, const float* __restrict__ Wgate,
                            unsigned short* __restrict__ q_ln, unsigned short* __restrict__ kv_ln,
                            float* __restrict__ bias, unsigned short* __restrict__ Wqkv_bf,
                            unsigned short* __restrict__ Wout_bf, unsigned short* __restrict__ Wgate_bf) {
    int blk = blockIdx.x;
    int t = threadIdx.x;
    if (blk >= 6144) {          // hoisted Wout/Wgate convert (only when launched)
        int idx = (blk - 6144) * 256 + t;
        const float* src; unsigned short* dst; int off;
        if (idx < 262144) { src = Wout; dst = Wout_bf; off = idx; }
        else              { src = Wgate; dst = Wgate_bf; off = idx - 262144; }
        float4 v = ((const float4*)src)[off];
        ushort4 u;
        u.x = f2bf(v.x); u.y = f2bf(v.y); u.z = f2bf(v.z); u.w = f2bf(v.w);
        ((ushort4*)dst)[off] = u;
        return;
    }
    if (blk >= 3072) {          // Wqkv convert
        int idx = (blk - 3072) * 256 + t;
        float4 v = ((const float4*)Wqkv)[idx];
        ushort4 u;
        u.x = f2bf(v.x); u.y = f2bf(v.y); u.z = f2bf(v.z); u.w = f2bf(v.w);
        ((ushort4*)Wqkv_bf)[idx] = u;
        return;
    }
    if (blk >= 2048) {          // bias
        int idx = (blk - 2048) * 256 + t;
        int qi = idx >> 9, kj = idx & 511;
        float fq = (qi + 0.5f) * 0.25f - 0.5f;
        float fk = (kj + 0.5f) * 0.25f - 0.5f;
        int iq = (int)floorf(fq); float tq = fq - (float)iq;
        int ik = (int)floorf(fk); float tk = fk - (float)ik;
        int iq0 = min(max(iq, 0), 127), iq1 = min(max(iq + 1, 0), 127);
        int ik0 = min(max(ik, 0), 127), ik1 = min(max(ik + 1, 0), 127);
        float v = (1.f - tq) * ((1.f - tk) * bias128(iq0, ik0) + tk * bias128(iq0, ik1))
                +        tq  * ((1.f - tk) * bias128(iq1, ik0) + tk * bias128(iq1, ik1));
        bias[idx] = v;
        return;
    }
    // LN: wave-per-row, shuffle-only reduction (R22)
    int row = blk * 4 + (t >> 6);
    int lane = t & 63;
    const float* src = (row < NROWS) ? dec + (size_t)row * D_MODEL
                                     : enc + (size_t)(row - NROWS) * D_MODEL;
    unsigned short* dst = (row < NROWS) ? q_ln + (size_t)row * D_MODEL
                                        : kv_ln + (size_t)(row - NROWS) * D_MODEL;
    float4 x0 = ((const float4*)src)[lane];
    float4 x1 = ((const float4*)src)[lane + 64];
    float4 x2 = ((const float4*)src)[lane + 128];
    float4 x3 = ((const float4*)src)[lane + 192];
    float s  = x0.x + x0.y + x0.z + x0.w + x1.x + x1.y + x1.z + x1.w
             + x2.x + x2.y + x2.z + x2.w + x3.x + x3.y + x3.z + x3.w;
    float ss = x0.x * x0.x + x0.y * x0.y + x0.z * x0.z + x0.w * x0.w
             + x1.x * x1.x + x1.y * x1.y + x1.z * x1.z + x1.w * x1.w
             + x2.x * x2.x + x2.y * x2.y + x2.z * x2.z + x2.w * x2.w
             + x3.x * x3.x + x3.y * x3.y + x3.z * x3.z + x3.w * x3.w;
    #pragma unroll
    for (int off = 32; off > 0; off >>= 1) {
        s  += __shfl_down(s, off);
        ss += __shfl_down(ss, off);
    }
    s  = __shfl(s, 0);
    ss = __shfl(ss, 0);
    float mu  = s * (1.0f / 1024.0f);
    float var = ss * (1.0f / 1024.0f) - mu * mu;
    float rstd = rsqrtf(var + LN_EPS);
    #pragma unroll
    for (int j = 0; j < 4; ++j) {
        float4 xv = (j == 0) ? x0 : (j == 1) ? x1 : (j == 2) ? x2 : x3;
        float4 g  = ((const float4*)gamma)[lane + j * 64];
        float4 bb = ((const float4*)beta)[lane + j * 64];
        ushort4 u;
        u.x = f2bf((xv.x - mu) * rstd * g.x + bb.x);
        u.y = f2bf((xv.y - mu) * rstd * g.y + bb.y);
        u.z = f2bf((xv.z - mu) * rstd * g.z + bb.z);
        u.w = f2bf((xv.w - mu) * rstd * g.w + bb.w);
        ((ushort4*)dst)[lane + j * 64] = u;
    }
}

// ---------------------------------------------------------------------------
// Wout + Wgate fp32 -> bf16 (fallback path when ws too small to hoist)
// ---------------------------------------------------------------------------
__global__ void convert_og(const float* __restrict__ Wout, const float* __restrict__ Wgate,
                           unsigned short* __restrict__ Wout_bf, unsigned short* __restrict__ Wgate_bf) {
    int idx = blockIdx.x * 256 + threadIdx.x;
    const float* src; unsigned short* dst; int off;
    if (idx < 262144) { src = (const float*)Wout; dst = Wout_bf; off = idx; }
    else              { src = (const float*)Wgate; dst = Wgate_bf; off = idx - 262144; }
    float4 v = ((const float4*)src)[off];
    ushort4 u;
    u.x = f2bf(v.x); u.y = f2bf(v.y); u.z = f2bf(v.z); u.w = f2bf(v.w);
    ((ushort4*)dst)[off] = u;
}

// ===========================================================================
// MFMA GEMM cores (bf16). Permanent lessons:
// R7/R16: accumulators and frags NAMED scalars (arrays spill to scratch).
// R9: global_load_lds + XOR swizzle (0 conflicts).
// R17: 128^2 tile latency-bound at K=1024. R18: attn KVBLK=128 regressed.
// R19: XCD ct-major swizzle FETCH 73->30MB. R20 NULL: counted-vmcnt on qkv.
// R21 WIN: qkv 24KB LDS / 6 blocks/CU: 49.2->44.0. R22 WIN: og 4/CU + prep
// wave-per-row LN: 207.8->203.1. R23 NULL (kept): attn XCD affinity, og BK=128.
// R24 FAILED (reverted): Wcomb fusion — qkv +6us (extra blocks pollute XCD L2
// partition), out_fused 3-operand staging worse barrier-to-work than og1+og2;
// total +20us. Lesson: fusion that adds per-step operands loses on this
// latency-dominated regime.
// ===========================================================================
#define CSTR 136   // C-bounce row stride (multiple of 8 -> 16B-aligned rows)

#define MF(a, b, d) __builtin_amdgcn_mfma_f32_16x16x32_bf16((a), (b), (d), 0, 0, 0)

// ---------------------------------------------------------------------------
// QKV GEMM (R21): 64x128 tile, BK=64 SINGLE-buffer (24 KB LDS -> 6 blocks/CU),
// fused RoPE. Q/K: (B,H,L,64). V: transposed (B,H,64,L) (R15).
// Grid 1536: XCD-contiguous swizzle, ct-major super-tiles (8ct x 4rt).
// ---------------------------------------------------------------------------
union alignas(16) SmemQS {
    struct { unsigned short A[64 * 64]; unsigned short B[128 * 64]; } ab;  // 24 KB
    unsigned short C[64 * CSTR];    // q/k bounce: 64 rows x 136 (17.4 KB)
    unsigned short Ct[128 * 72];    // v bounce (transposed): 128 d-rows x 72 (18.4 KB)
};

// one K-half (K=32) of a BK=64 step: 6 frag loads + 8 MFMA
#define QKH(pA, pB, kh)                                                        \
    {                                                                          \
        int pofs = (((kh) * 4 + quad) ^ x7) * 8;                               \
        const unsigned short* Ar_ = (pA) + (wr * 32 + c) * 64 + pofs;          \
        const unsigned short* Br_ = (pB) + (wc * 64 + c) * 64 + pofs;          \
        bf16x8 f0 = *(const bf16x8*)(Ar_);                                     \
        bf16x8 f1 = *(const bf16x8*)(Ar_ + 1024);                              \
        bf16x8 g0 = *(const bf16x8*)(Br_);                                     \
        bf16x8 g1 = *(const bf16x8*)(Br_ + 1024);                              \
        bf16x8 g2 = *(const bf16x8*)(Br_ + 2048);                              \
        bf16x8 g3 = *(const bf16x8*)(Br_ + 3072);                              \
        c00 = MF(f0, g0, c00); c01 = MF(f0, g1, c01); c02 = MF(f0, g2, c02); c03 = MF(f0, g3, c03); \
        c10 = MF(f1, g0, c10); c11 = MF(f1, g1, c11); c12 = MF(f1, g2, c12); c13 = MF(f1, g3, c13); \
    }

#define QROPE_REG(i, reg, A0, A1, A2, A3)                                      \
    {                                                                          \
        int mloc = wr * 32 + (i) * 16 + quad * 4 + (reg);                      \
        int crow = mloc * CSTR + wc * 64;                                      \
        float fl = (float)((rt * 64 + mloc) & 511);                            \
        float aa0 = fl * inv0, aa1 = fl * inv1;                                \
        float c0 = cosf(aa0), s0 = sinf(aa0);                                  \
        float c1 = cosf(aa1), s1 = sinf(aa1);                                  \
        float e0 = A0[(reg)], o0 = A2[(reg)];                                  \
        float e1 = A1[(reg)], o1 = A3[(reg)];                                  \
        smemq.C[crow + c]      = f2bf(e0 * c0 - o0 * s0);                      \
        smemq.C[crow + 32 + c] = f2bf(e0 * s0 + o0 * c0);                      \
        smemq.C[crow + 16 + c] = f2bf(e1 * c1 - o1 * s1);                      \
        smemq.C[crow + 48 + c] = f2bf(e1 * s1 + o1 * c1);                      \
    }
#define QROPE_ROW(i, A0, A1, A2, A3)                                           \
    QROPE_REG(i, 0, A0, A1, A2, A3) QROPE_REG(i, 1, A0, A1, A2, A3)            \
    QROPE_REG(i, 2, A0, A1, A2, A3) QROPE_REG(i, 3, A0, A1, A2, A3)

// V: bounce transposed — Ct[dcol][l_local], stride 72
#define QVSECT_REG(i, j, reg, Acc)                                             \
    smemq.Ct[(wc * 64 + (j) * 16 + c) * 72 + (wr * 32 + (i) * 16 + quad * 4 + (reg))] = f2bf(Acc[(reg)]);
#define QVSECT_TILE(i, j, Acc)                                                 \
    QVSECT_REG(i, j, 0, Acc) QVSECT_REG(i, j, 1, Acc)                          \
    QVSECT_REG(i, j, 2, Acc) QVSECT_REG(i, j, 3, Acc)

__global__ __launch_bounds__(256, 6)
void qkv_gemm_mfma(const unsigned short* __restrict__ q_ln,
                   const unsigned short* __restrict__ kv_ln,
                   const unsigned short* __restrict__ Wb,
                   unsigned short* __restrict__ qo,
                   unsigned short* __restrict__ ko,
                   unsigned short* __restrict__ vo) {
    int bid = blockIdx.x;                     // 0..1535
    int wg = (bid & 7) * 192 + (bid >> 3);    // XCD-contiguous (bijective, 1536%8==0)
    int st = wg >> 5, in = wg & 31;           // 48 super-tiles of 32 blocks
    int stc = st >> 4, str = st & 15;         // ct-major: stc 0..2 (= section), str 0..15
    int ct = stc * 8 + (in & 7);              // 0..23
    int rt = str * 4 + (in >> 3);             // 0..63
    int n0 = ct * 128;
    int section = stc;                        // 0=q 1=k 2=v
    const unsigned short* A = (section == 0) ? q_ln : kv_ln;

    __shared__ SmemQS smemq;
    unsigned short* As2 = smemq.ab.A;
    unsigned short* Bs2 = smemq.ab.B;
    int tid = threadIdx.x;
    int wave = tid >> 6, lane = tid & 63, quad = lane >> 4, c = lane & 15;
    int wr = wave >> 1, wc = wave & 1;
    int x7 = c & 7;

    // staging source: thread t covers row t>>3, slot t&7 holds chunk (t&7)^((t>>3)&7)
    int soff = (tid >> 3) * 1024 + (((tid & 7) ^ ((tid >> 3) & 7)) * 8);
    const unsigned short* Ab = A + (size_t)(rt * 64) * 1024 + soff;
    const unsigned short* Bb = Wb + (size_t)n0 * 1024 + soff;
    int stW = wave * 512;

    f32x4 c00 = (f32x4)0.f, c01 = (f32x4)0.f, c02 = (f32x4)0.f, c03 = (f32x4)0.f;
    f32x4 c10 = (f32x4)0.f, c11 = (f32x4)0.f, c12 = (f32x4)0.f, c13 = (f32x4)0.f;

    // Single-buffer BK=64 K-loop (16 steps): cross-block TLP (6 blocks/CU)
    // hides the per-step stalls; no in-block pipeline (R20 proved it null).
    for (int kt = 0; kt < 16; ++kt) {
        int k0 = kt * 64;
        __syncthreads();
        GLOAD16(Ab + k0,          As2 + stW);
        GLOAD16(Ab + 32768 + k0,  As2 + stW + 2048);
        GLOAD16(Bb + k0,          Bs2 + stW);
        GLOAD16(Bb + 32768 + k0,  Bs2 + stW + 2048);
        GLOAD16(Bb + 65536 + k0,  Bs2 + stW + 4096);
        GLOAD16(Bb + 98304 + k0,  Bs2 + stW + 6144);
        __syncthreads();
        QKH(As2, Bs2, 0)
        QKH(As2, Bs2, 1)
    }

    __syncthreads();                    // all waves done reading As/Bs (union reuse)

    if (section == 2) {
        QVSECT_TILE(0, 0, c00) QVSECT_TILE(0, 1, c01) QVSECT_TILE(0, 2, c02) QVSECT_TILE(0, 3, c03)
        QVSECT_TILE(1, 0, c10) QVSECT_TILE(1, 1, c11) QVSECT_TILE(1, 2, c12) QVSECT_TILE(1, 3, c13)
        __syncthreads();
        // store: 128 d-rows x 64 contiguous l
        int dr = tid >> 1, hh = tid & 1;
        int h = ((n0 & 1023) >> 6) + (dr >> 6);
        int d = dr & 63;
        int mmb = rt * 64;
        int bb = mmb >> 9, ll0 = mmb & 511;
        unsigned short* orow = vo + (((size_t)bb * NHEADS + h) * HDIM + d) * SEQ + ll0 + hh * 32;
        const unsigned short* csrc = &smemq.Ct[dr * 72 + hh * 32];
        #pragma unroll
        for (int kc = 0; kc < 4; ++kc)
            *(u16x8*)(orow + kc * 8) = *(const u16x8*)(csrc + kc * 8);
        return;
    }

    float inv0 = expf(-0.2878231366f * (float)c);          // 10000^(-c/32)
    float inv1 = expf(-0.2878231366f * (float)(16 + c));
    QROPE_ROW(0, c00, c01, c02, c03)
    QROPE_ROW(1, c10, c11, c12, c13)
    __syncthreads();

    unsigned short* outp = (section == 0) ? qo : ko;
    int rr = tid >> 2;                  // row 0..63
    int ch = (tid >> 1) & 1;            // head-half 0/1
    int sub = tid & 1;                  // 32-short half within head
    int mm = rt * 64 + rr;
    int bb = mm >> 9, ll = mm & 511;
    int h = ((n0 & 1023) >> 6) + ch;
    unsigned short* orow = outp + (((size_t)bb * NHEADS + h) * SEQ + ll) * HDIM + sub * 32;
    const unsigned short* csrc = &smemq.C[rr * CSTR + ch * 64 + sub * 32];
    #pragma unroll
    for (int kc = 0; kc < 4; ++kc)
        *(u16x8*)(orow + kc * 8) = *(const u16x8*)(csrc + kc * 8);
}

// ---------------------------------------------------------------------------
// Out-projection GEMMs (R23): 64x64 tile, BK=128 single-buffer (32 KB LDS),
// grid 1024 (1-D, XCD-contiguous swizzle). 4 blocks/CU.
// Staging: 128-col rows, 16 slots, chunk = slot ^ (row&15); read
// pofs = ((kh*4+quad) ^ c)*8 (proven R0 scheme). Wave tile 32x32.
// ---------------------------------------------------------------------------
struct alignas(16) SmemOG {
    unsigned short A[64 * 128];     // 16 KB
    unsigned short B[64 * 128];     // 16 KB
};

#define OG_KH(kh)                                                              \
    {                                                                          \
        int pofs = (((kh) * 4 + quad) ^ c) * 8;                                \
        const unsigned short* Ar_ = smemog.A + (wr * 32 + c) * 128 + pofs;     \
        const unsigned short* Br_ = smemog.B + (wc * 32 + c) * 128 + pofs;     \
        bf16x8 f0 = *(const bf16x8*)(Ar_);                                     \
        bf16x8 f1 = *(const bf16x8*)(Ar_ + 2048);                              \
        bf16x8 g0 = *(const bf16x8*)(Br_);                                     \
        bf16x8 g1 = *(const bf16x8*)(Br_ + 2048);                              \
        c00 = MF(f0, g0, c00); c01 = MF(f0, g1, c01);                          \
        c10 = MF(f1, g0, c10); c11 = MF(f1, g1, c11);                          \
    }

#define OG_BODY(Aptr, Bptr)                                                    \
    int bid = blockIdx.x;                     /* 0..1023 */                    \
    int wg = (bid & 7) * 128 + (bid >> 3);    /* XCD-contiguous, bijective */  \
    int ct = wg & 15, rt = wg >> 4;                                            \
    int tid = threadIdx.x;                                                     \
    int wave = tid >> 6, lane = tid & 63, quad = lane >> 4, c = lane & 15;     \
    int wr = wave >> 1, wc = wave & 1;                                         \
    /* staging: thread t -> row t>>4 (+16/call), slot t&15; chunk = slot^(row&15) */ \
    int soff = (tid >> 4) * 1024 + (((tid & 15) ^ ((tid >> 4) & 15)) * 8);     \
    const unsigned short* Ab = (Aptr) + (size_t)(rt * 64) * 1024 + soff;       \
    const unsigned short* Bb = (Bptr) + (size_t)(ct * 64) * 1024 + soff;       \
    int stW = wave * 512;                                                      \
    f32x4 c00 = (f32x4)0.f, c01 = (f32x4)0.f;                                  \
    f32x4 c10 = (f32x4)0.f, c11 = (f32x4)0.f;                                  \
    for (int kt = 0; kt < 8; ++kt) {                                           \
        int k0 = kt * 128;                                                     \
        __syncthreads();                                                       \
        GLOAD16(Ab + k0,          smemog.A + stW);                             \
        GLOAD16(Ab + 16384 + k0,  smemog.A + stW + 2048);                      \
        GLOAD16(Ab + 32768 + k0,  smemog.A + stW + 4096);                      \
        GLOAD16(Ab + 49152 + k0,  smemog.A + stW + 6144);                      \
        GLOAD16(Bb + k0,          smemog.B + stW);                             \
        GLOAD16(Bb + 16384 + k0,  smemog.B + stW + 2048);                      \
        GLOAD16(Bb + 32768 + k0,  smemog.B + stW + 4096);                      \
        GLOAD16(Bb + 49152 + k0,  smemog.B + stW + 6144);                      \
        __syncthreads();                                                       \
        OG_KH(0)                                                               \
        OG_KH(1)                                                               \
        OG_KH(2)                                                               \
        OG_KH(3)                                                               \
    }

#define O1_REG(mb, reg, n, Acc)                                                \
    t_bf[(size_t)((mb) + (reg)) * 1024 + (n)] = f2bf(Acc[(reg)] + bo);
#define O1_TILE(i, j, Acc)                                                     \
    {                                                                          \
        int n = ct * 64 + wc * 32 + (j) * 16 + c;                              \
        float bo = b_out[n];                                                   \
        int mb = rt * 64 + wr * 32 + (i) * 16 + quad * 4;                      \
        O1_REG(mb, 0, n, Acc) O1_REG(mb, 1, n, Acc)                            \
        O1_REG(mb, 2, n, Acc) O1_REG(mb, 3, n, Acc)                            \
    }

__global__ __launch_bounds__(256, 4)
void out_gemm1_mfma(const unsigned short* __restrict__ att,
                    const unsigned short* __restrict__ Wob,
                    const float* __restrict__ b_out,
                    unsigned short* __restrict__ t_bf) {
    __shared__ SmemOG smemog;
    OG_BODY(att, Wob)
    O1_TILE(0, 0, c00) O1_TILE(0, 1, c01)
    O1_TILE(1, 0, c10) O1_TILE(1, 1, c11)
}

#define O2_REG(mb, reg, n, Acc)                                                \
    {                                                                          \
        float gz = Acc[(reg)] + bg;                                            \
        float g = 1.0f / (1.0f + expf(-gz));                                   \
        size_t idx = (size_t)((mb) + (reg)) * 1024 + (n);                      \
        float tv = bf2f(t_bf[idx]);                                            \
        float rv = residual[idx];                                              \
        out[idx] = g * tv + (1.0f - g) * rv;                                   \
    }
#define O2_TILE(i, j, Acc)                                                     \
    {                                                                          \
        int n = ct * 64 + wc * 32 + (j) * 16 + c;                              \
        float bg = b_gate[n];                                                  \
        int mb = rt * 64 + wr * 32 + (i) * 16 + quad * 4;                      \
        O2_REG(mb, 0, n, Acc) O2_REG(mb, 1, n, Acc)                            \
        O2_REG(mb, 2, n, Acc) O2_REG(mb, 3, n, Acc)                            \
    }

__global__ __launch_bounds__(256, 4)
void out_gemm2_mfma(const unsigned short* __restrict__ t_bf,
                    const unsigned short* __restrict__ Wgb,
                    const float* __restrict__ b_gate,
                    const float* __restrict__ residual,
                    float* __restrict__ out) {
    __shared__ SmemOG smemog;
    OG_BODY(t_bf, Wgb)
    O2_TILE(0, 0, c00) O2_TILE(0, 1, c01)
    O2_TILE(1, 0, c10) O2_TILE(1, 1, c11)
}

// ---------------------------------------------------------------------------
// Flash attention (R23), bf16 MFMA (16x16x32). 128-row Q tile, 8 waves.
// R12: unnormalized streaming softmax. R15: K/Vt via global_load_lds + XOR
// swizzle. R20: counted-vmcnt dbuf. R23: qt-major 1-D grid (bid = qt*128+hb,
// bid%8 == hb%8) -> all 4 qt-blocks of a head on the SAME XCD.
// ---------------------------------------------------------------------------
#define KSTR 72   // Ps stride only

static __device__ __forceinline__ void attn_step(
    const unsigned short* __restrict__ KsB, const unsigned short* __restrict__ VsB,
    int kv0, const float* __restrict__ bias, unsigned short* __restrict__ Ps,
    int q0, int wb, int quad, int c, int p0, int p1,
    bf16x8 aq0, bf16x8 aq1, f32x4 (&oacc)[4], float (&lrow)[4])
{
    f32x4 sacc[4];
    #pragma unroll
    for (int nt = 0; nt < 4; ++nt) {
        const unsigned short* kbase = &KsB[(nt * 16 + c) * 64];
        bf16x8 b0 = *(const bf16x8*)(kbase + p0);
        bf16x8 b1 = *(const bf16x8*)(kbase + p1);
        f32x4 a = (f32x4)0.f;
        a = __builtin_amdgcn_mfma_f32_16x16x32_bf16(aq0, b0, a, 0, 0, 0);
        a = __builtin_amdgcn_mfma_f32_16x16x32_bf16(aq1, b1, a, 0, 0, 0);
        sacc[nt] = a;
    }
    const float* bbase = bias + (size_t)(q0 + wb + quad * 4) * 512 + kv0 + c;
    float tsum[4];
    #pragma unroll
    for (int r = 0; r < 4; ++r) tsum[r] = 0.f;
    #pragma unroll
    for (int nt = 0; nt < 4; ++nt)
        #pragma unroll
        for (int r = 0; r < 4; ++r) {
            float p = __expf(sacc[nt][r] * SCALE + bbase[(size_t)r * 512 + nt * 16]);
            tsum[r] += p;
            Ps[(wb + quad * 4 + r) * KSTR + nt * 16 + c] = f2bf(p);
        }
    #pragma unroll
    for (int r = 0; r < 4; ++r) {
        float t = tsum[r];
        t += __shfl_xor(t, 1);
        t += __shfl_xor(t, 2);
        t += __shfl_xor(t, 4);
        t += __shfl_xor(t, 8);
        lrow[r] += t;
    }
    bf16x8 pb0 = *(const bf16x8*)&Ps[(wb + c) * KSTR + quad * 8];
    bf16x8 pb1 = *(const bf16x8*)&Ps[(wb + c) * KSTR + 32 + quad * 8];
    #pragma unroll
    for (int t = 0; t < 4; ++t) {
        const unsigned short* vbase = &VsB[(t * 16 + c) * 64];
        bf16x8 a0 = *(const bf16x8*)(vbase + p0);
        bf16x8 a1 = *(const bf16x8*)(vbase + p1);
        oacc[t] = __builtin_amdgcn_mfma_f32_16x16x32_bf16(a0, pb0, oacc[t], 0, 0, 0);
        oacc[t] = __builtin_amdgcn_mfma_f32_16x16x32_bf16(a1, pb1, oacc[t], 0, 0, 0);
    }
}

// stage KV tile kvt into buffer BUF (2 loads/lane)
#define ASTAGE(BUF, kvt)                                                       \
    GLOAD16(kgb + (size_t)((kvt) * 64) * HDIM, Ks[BUF] + wave * 512);          \
    GLOAD16(vgb + (kvt) * 64, Vs[BUF] + wave * 512);

__global__ __launch_bounds__(512)
void attn_kernel(const unsigned short* __restrict__ q,
                 const unsigned short* __restrict__ k,
                 const unsigned short* __restrict__ vt,
                 const float* __restrict__ bias,
                 unsigned short* __restrict__ attended) {
    int bid = blockIdx.x;               // 0..511 (qt-major: bid%8 == hb%8)
    int qt = bid >> 7;                  // 0..3
    int hb = bid & 127;                 // 0..127
    int h = hb >> 3;                    // 0..15
    int b = hb & 7;                     // 0..7
    __shared__ unsigned short Ks[2][64 * 64];
    __shared__ unsigned short Vs[2][64 * 64];
    __shared__ unsigned short Ps[128 * KSTR];
    __shared__ float lf[128];

    int tid = threadIdx.x;
    int wave = tid >> 6, lane = tid & 63;   // wave 0..7
    int quad = lane >> 4, c = lane & 15;
    int wb = wave * 16;                     // wave's q-row base, 0..112
    size_t headbase = (((size_t)b * NHEADS + h) * SEQ) * HDIM;  // == (b*16+h)*32768
    int q0 = qt * 128;

    const unsigned short* qrow = q + headbase + (size_t)(q0 + wb + c) * HDIM;
    bf16x8 aq0 = *(const bf16x8*)(qrow + quad * 8);
    bf16x8 aq1 = *(const bf16x8*)(qrow + 32 + quad * 8);

    // staging: wave w covers rows w*8..w*8+7 (8 rows x 64 shorts = 1 GLOAD16/lane)
    int srow = wave * 8 + (lane >> 3);
    int schunk = (lane & 7) ^ (srow & 7);
    const unsigned short* kgb = k + headbase + (size_t)srow * HDIM + schunk * 8;
    const unsigned short* vgb = vt + headbase + (size_t)srow * SEQ + schunk * 8;
    int x7 = c & 7;
    int p0 = (quad ^ x7) * 8;
    int p1 = ((4 + quad) ^ x7) * 8;

    f32x4 oacc[4];
    #pragma unroll
    for (int t = 0; t < 4; ++t) oacc[t] = (f32x4)0.f;
    float lrow[4];
    #pragma unroll
    for (int r = 0; r < 4; ++r) lrow[r] = 0.f;

    // Counted-vmcnt dbuf pipeline: 8 KV tiles of 64, 2 loads/stage.
    ASTAGE(0, 0)
    ASTAGE(1, 1)
    VMW(2); RBAR();                               // tile0 ready (Q loads also drained)
    for (int kt2 = 0; kt2 < 4; ++kt2) {
        attn_step(Ks[0], Vs[0], (kt2 * 2) * 64, bias, Ps,
                  q0, wb, quad, c, p0, p1, aq0, aq1, oacc, lrow);
        RBAR();                                   // all waves done reading buf0
        if (kt2 < 3) { ASTAGE(0, kt2 * 2 + 2) VMW(2); }
        else         { VMW(0); }                  // tile7's loads must land
        RBAR();                                   // buf1 ready
        attn_step(Ks[1], Vs[1], (kt2 * 2 + 1) * 64, bias, Ps,
                  q0, wb, quad, c, p0, p1, aq0, aq1, oacc, lrow);
        RBAR();                                   // all waves done reading buf1
        if (kt2 < 3) { ASTAGE(1, kt2 * 2 + 3) VMW(2); }
        RBAR();                                   // buf0 ready (next iter)
    }

    if (c == 0) {
        f32x4 lv;
        lv[0] = lrow[0]; lv[1] = lrow[1]; lv[2] = lrow[2]; lv[3] = lrow[3];
        *(f32x4*)&lf[wb + quad * 4] = lv;
    }
    float invl = 1.0f / lf[wb + c];
    unsigned short* drow = attended + ((size_t)b * SEQ + (q0 + wb + c)) * D_MODEL + h * HDIM;
    #pragma unroll
    for (int t = 0; t < 4; ++t) {
        ushort4 o;
        o.x = f2bf(oacc[t][0] * invl);
        o.y = f2bf(oacc[t][1] * invl);
        o.z = f2bf(oacc[t][2] * invl);
        o.w = f2bf(oacc[t][3] * invl);
        *(ushort4*)(drow + t * 16 + quad * 4) = o;
    }
}

extern "C" void kernel_launch(void* const* d_in, const int* in_sizes, int n_in,
                              void* d_out, int out_size, void* d_ws, size_t ws_size,
                              hipStream_t stream) {
    const float* dec    = (const float*)d_in[0];
    const float* enc    = (const float*)d_in[1];
    const float* Wqkv   = (const float*)d_in[2];
    const float* Wout   = (const float*)d_in[3];
    const float* b_out  = (const float*)d_in[4];
    const float* Wgate  = (const float*)d_in[5];
    const float* b_gate = (const float*)d_in[6];
    const float* gamma  = (const float*)d_in[7];
    const float* beta   = (const float*)d_in[8];
    float* out = (float*)d_out;

    char* ws = (char*)d_ws;
    const size_t MB = 1024 * 1024;
    unsigned short* q_ln    = (unsigned short*)(ws + 0 * MB);
    unsigned short* kv_ln   = (unsigned short*)(ws + 8 * MB);
    unsigned short* qb      = (unsigned short*)(ws + 16 * MB);
    unsigned short* kb      = (unsigned short*)(ws + 24 * MB);
    unsigned short* vb      = (unsigned short*)(ws + 32 * MB);   // V^T (B,H,64,L)
    unsigned short* Wqkv_bf = (unsigned short*)(ws + 40 * MB);
    float*          bias    = (float*)(ws + 46 * MB);
    unsigned short* att     = (unsigned short*)(ws + 0 * MB);    // q_ln dead after qkv
    unsigned short* t_bf    = (unsigned short*)(ws + 24 * MB);   // kb dead after attn

    // Hoisted weight-convert needs 4 MB of never-aliased space at 47..51 MB.
    bool hoist = (ws_size >= 51 * MB);
    unsigned short* Wout_bf  = (unsigned short*)(ws + (hoist ? 47 * MB : 32 * MB));
    unsigned short* Wgate_bf = (unsigned short*)(ws + (hoist ? 49 * MB : 34 * MB));

    prep_kernel<<<hoist ? 8192 : 6144, 256, 0, stream>>>(
        dec, enc, gamma, beta, Wqkv, Wout, Wgate,
        q_ln, kv_ln, bias, Wqkv_bf, Wout_bf, Wgate_bf);
    qkv_gemm_mfma<<<1536, 256, 0, stream>>>(q_ln, kv_ln, Wqkv_bf, qb, kb, vb);
    attn_kernel<<<512, 512, 0, stream>>>(qb, kb, vb, bias, att);
    if (!hoist)
        convert_og<<<2048, 256, 0, stream>>>(Wout, Wgate, Wout_bf, Wgate_bf);
    out_gemm1_mfma<<<1024, 256, 0, stream>>>(att, Wout_bf, b_out, t_bf);
    out_gemm2_mfma<<<1024, 256, 0, stream>>>(t_bf, Wgate_bf, b_gate, dec, out);
}